// Round 4
// baseline (543.076 us; speedup 1.0000x reference)
//
#include <hip/hip_runtime.h>

// ---------------------------------------------------------------------------
// GNN forward, MI355X. All I/O f32. R4: full f32-accuracy numerics.
// The GRU gates are saturated switches (pre-activations ~1e4): f16-class
// (5e-4) staging flips gates near the switch point -> chaotic 16% error
// (R3's absmax 856). All activations/state now f32; the big edge-MLP
// matmuls keep MFMA via 3-term split-f16 (Markidis): A=Ah+Al, B=Bh+Bl,
// C ~= AhBh+AhBl+AlBh, f32 accumulate -> rel err ~2^-22 (f32-class).
// Activation splits carry an exact /64 scale for f16 range safety; weight
// splits are unscaled (|w|<2). Small matmuls (GRU gates, node update,
// readout) are plain f32 VALU dot products.
//   k_pre : fc1a f32 -> node ws; h -> ws; weight transposes (f32) and
//           hi/lo f16 split pairs for the MFMA matmuls.
//   k_iter x3 (block = batch x 16-src-node group):
//     P0: node -> /64 hi/lo LDS splits. P1: Q,P (f32 LDS) via split-MFMA.
//     P2: 16 chunks (1 node = 64 edge slots): m1 = gelu(Q[i]+P[j]+e.w+b)
//         in f32 -> hi/lo; mm2/mm3 via split-MFMA; f32 segment-sum (LDS
//         atomics). P3: GRU gates f32 VALU. P4: node update / readout.
// ---------------------------------------------------------------------------

typedef _Float16 f16;
typedef _Float16 h8 __attribute__((ext_vector_type(8)));
typedef float f4 __attribute__((ext_vector_type(4)));

#define MFMA16(a, b, c) __builtin_amdgcn_mfma_f32_16x16x32_f16(a, b, c, 0, 0, 0)

// ---- workspace byte offsets ----
#define H_OFF 0              // f32 [128][64][64]
#define NODEA_OFF 2097152    // f32 [128][64][32]
#define NODEB_OFF 3145728    // f32 [128][64][32]
#define WQ_OFF 4194304
// within WQ:
#define O_W2ALOH 0       // f16 [64u][32k] hi of W2a[k][u], k<32
#define O_W2ALOL 4096    // f16 lo
#define O_W2AHIH 8192    // f16 [64u][32k] hi of W2a[32+k][u]
#define O_W2AHIL 12288
#define O_W45B 16384     // f32 w64[64], w65[64], b2a[64]
#define O_W2BTH 17152    // f16 [32v][64k] hi of W2b[k][v]
#define O_W2BTL 21248
#define O_B2B 25344      // f32 [32]
#define O_W2CTH 25472    // f16 [32v][32k]
#define O_W2CTL 27520
#define O_B2C 29568      // f32 [32]
#define O_WXT 29696      // f32 [192u][32k] = Wx[k][u]
#define O_UXT 54272      // f32 [192u][64k] = Ux[k][u]
#define O_BX 103424      // f32 [192]
#define O_BH 104192      // f32 [192]
#define O_W3BT 104960    // f32 [32f][64k] = W3b[k][f]
#define O_B3B 113152     // f32 [32]
#define O_W4AT 113280    // f32 [64u][32k] = W4a[k][u]
#define O_B4A 121472     // f32 [64]
#define O_W4BT 121728    // f32 [32v][64k] = W4b[k][v]
#define O_B4B 129920     // f32 [32]
#define O_W4CT 130048    // f32 [32f][32k] = W4c[k][f]
#define O_B4C 134144     // f32 [32]

// ---- k_iter LDS byte offsets ----
#define L_NH 0       // f16 [64][32]  node/64 hi
#define L_NL 4096    // f16 [64][32]  node/64 lo
#define L_QF 8192    // f32 [16][66]  Q (raw scale)
#define L_PF 12416   // f32 [64][66]  P (raw scale)
#define L_MACC 29312 // f32 [16][32]  m_i accumulators (raw)
#define L_M1H 31360  // f16 [64][72]  m1/64 hi (per chunk)
#define L_M1L 40576  // f16 [64][72]  m1/64 lo
#define L_M2H 49792  // f16 [64][40]  m2/64 hi
#define L_M2L 54912  // f16 [64][40]  m2/64 lo
#define L_TOTAL 60032
// overlays (M1/M2 region dead after P2):
#define L_H32 31360  // f32 [16][64] h old
#define L_R 35456    // f32 [16][64]
#define L_Z 39552    // f32 [16][64]
#define L_XN 43648   // f32 [16][64]
#define L_HNG 47744  // f32 [16][64]
#define L_HN32 51840 // f32 [16][64] h new
// readout overlays (R/Z/XN/HNG dead after h-update):
#define L_T1 35456   // f32 [16][68]
#define L_T2 43648   // f32 [16][36]
#define L_ND 47744   // f32 [16][32]

__device__ __forceinline__ float fast_rcp(float x) {
#if __has_builtin(__builtin_amdgcn_rcpf)
  return __builtin_amdgcn_rcpf(x);
#else
  return 1.0f / x;
#endif
}
// jax.nn.gelu(approximate=True) = x*sigmoid(2*sqrt(2/pi)*(x+0.044715x^3))
__device__ __forceinline__ float gelu_f(float x) {
  float x3 = x * x * x;
  float u = -1.5957691216057308f * fmaf(0.044715f, x3, x);
  return x * fast_rcp(1.f + __expf(u));
}
__device__ __forceinline__ float sigm_f(float x) {
  return fast_rcp(1.f + __expf(-x));
}
// unscaled hi/lo split (weights, |w| small)
__device__ __forceinline__ void splitw(float v, f16& h, f16& l) {
  h = (f16)v;
  l = (f16)(v - (float)h);
}
// /64-scaled hi/lo split (activations)
__device__ __forceinline__ void splita(float v, f16& h, f16& l) {
  float s = v * 0.015625f;
  h = (f16)s;
  l = (f16)(s - (float)h);
}

// ===========================================================================
__global__ __launch_bounds__(256) void k_pre(
    const float* __restrict__ node0, const float* __restrict__ hin,
    const float* __restrict__ W1, const float* __restrict__ b1,
    const float* __restrict__ W2a, const float* __restrict__ b2a,
    const float* __restrict__ W2b, const float* __restrict__ b2b,
    const float* __restrict__ W2c, const float* __restrict__ b2c,
    const float* __restrict__ Wx, const float* __restrict__ Ux,
    const float* __restrict__ bx, const float* __restrict__ bh,
    const float* __restrict__ W3b, const float* __restrict__ b3b,
    const float* __restrict__ W4a, const float* __restrict__ b4a,
    const float* __restrict__ W4b, const float* __restrict__ b4b,
    const float* __restrict__ W4c, const float* __restrict__ b4c,
    float* __restrict__ ws) {
  const int t = threadIdx.x;
  const int blk = blockIdx.x;
  char* wsb = (char*)ws;
  float* nodeA = (float*)(wsb + NODEA_OFF);
  float* h_ws = (float*)(wsb + H_OFF);
  char* W = wsb + WQ_OFF;

  if (blk < 128) {
    const int b = blk;
    for (int idx = t; idx < 2048; idx += 256) {
      const int n = idx >> 5, f = idx & 31;
      float acc = b1[f];
#pragma unroll
      for (int k = 0; k < 8; ++k)
        acc = fmaf(node0[((size_t)(b * 64 + n)) * 8 + k], W1[k * 32 + f], acc);
      nodeA[(size_t)b * 2048 + idx] = acc;
    }
    for (int idx = t; idx < 4096; idx += 256)
      h_ws[(size_t)b * 4096 + idx] = hin[(size_t)b * 4096 + idx];
  } else if (blk == 128) {
    f16* loh = (f16*)(W + O_W2ALOH);
    f16* lol = (f16*)(W + O_W2ALOL);
    f16* hih = (f16*)(W + O_W2AHIH);
    f16* hil = (f16*)(W + O_W2AHIL);
    for (int idx = t; idx < 2048; idx += 256) {
      const int k = idx >> 6, u = idx & 63;
      f16 h_, l_;
      splitw(W2a[k * 64 + u], h_, l_);
      loh[u * 32 + k] = h_;
      lol[u * 32 + k] = l_;
      splitw(W2a[(k + 32) * 64 + u], h_, l_);
      hih[u * 32 + k] = h_;
      hil[u * 32 + k] = l_;
    }
    float* wb = (float*)(W + O_W45B);
    if (t < 64) {
      wb[t] = W2a[64 * 64 + t];
      wb[64 + t] = W2a[65 * 64 + t];
      wb[128 + t] = b2a[t];
    }
    f16* bth = (f16*)(W + O_W2BTH);
    f16* btl = (f16*)(W + O_W2BTL);
    for (int idx = t; idx < 2048; idx += 256) {
      const int k = idx >> 5, v = idx & 31;
      f16 h_, l_;
      splitw(W2b[k * 32 + v], h_, l_);
      bth[v * 64 + k] = h_;
      btl[v * 64 + k] = l_;
    }
    float* b2bf = (float*)(W + O_B2B);
    if (t < 32) b2bf[t] = b2b[t];
    f16* cth = (f16*)(W + O_W2CTH);
    f16* ctl = (f16*)(W + O_W2CTL);
    for (int idx = t; idx < 1024; idx += 256) {
      const int k = idx >> 5, v = idx & 31;
      f16 h_, l_;
      splitw(W2c[k * 32 + v], h_, l_);
      cth[v * 32 + k] = h_;
      ctl[v * 32 + k] = l_;
    }
    float* b2cf = (float*)(W + O_B2C);
    if (t < 32) b2cf[t] = b2c[t];
  } else if (blk == 129) {
    float* wxt = (float*)(W + O_WXT);
    for (int idx = t; idx < 6144; idx += 256) {
      const int u = idx >> 5, k = idx & 31;
      wxt[u * 32 + k] = Wx[k * 192 + u];
    }
    float* bxf = (float*)(W + O_BX);
    float* bhf = (float*)(W + O_BH);
    if (t < 192) {
      bxf[t] = bx[t];
      bhf[t] = bh[t];
    }
  } else if (blk == 130) {
    float* uxt = (float*)(W + O_UXT);
    for (int idx = t; idx < 12288; idx += 256) {
      const int u = idx >> 6, k = idx & 63;
      uxt[u * 64 + k] = Ux[k * 192 + u];
    }
  } else {
    float* w3bt = (float*)(W + O_W3BT);
    for (int idx = t; idx < 2048; idx += 256) {
      const int f = idx >> 6, k = idx & 63;
      w3bt[f * 64 + k] = W3b[k * 32 + f];
    }
    float* b3bf = (float*)(W + O_B3B);
    if (t < 32) b3bf[t] = b3b[t];
    float* w4at = (float*)(W + O_W4AT);
    for (int idx = t; idx < 2048; idx += 256) {
      const int u = idx >> 5, k = idx & 31;
      w4at[u * 32 + k] = W4a[k * 64 + u];
    }
    float* b4af = (float*)(W + O_B4A);
    if (t < 64) b4af[t] = b4a[t];
    float* w4bt = (float*)(W + O_W4BT);
    for (int idx = t; idx < 2048; idx += 256) {
      const int v = idx >> 6, k = idx & 63;
      w4bt[v * 64 + k] = W4b[k * 32 + v];
    }
    float* b4bf = (float*)(W + O_B4B);
    if (t < 32) b4bf[t] = b4b[t];
    float* w4ct = (float*)(W + O_W4CT);
    for (int idx = t; idx < 1024; idx += 256) {
      const int f = idx >> 5, k = idx & 31;
      w4ct[f * 32 + k] = W4c[k * 32 + f];
    }
    float* b4cf = (float*)(W + O_B4C);
    if (t < 32) b4cf[t] = b4c[t];
  }
}

// ===========================================================================
__global__ __launch_bounds__(256) void k_iter(
    const float* __restrict__ edge, float* __restrict__ ws,
    const float* __restrict__ node_in, float* __restrict__ node_out,
    float* __restrict__ out, const int is_last) {
  __shared__ alignas(16) char sm[L_TOTAL];
  f16* sNH = (f16*)(sm + L_NH);
  f16* sNL = (f16*)(sm + L_NL);
  float* sQf = (float*)(sm + L_QF);
  float* sPf = (float*)(sm + L_PF);
  float* sMacc = (float*)(sm + L_MACC);
  f16* sM1H = (f16*)(sm + L_M1H);
  f16* sM1L = (f16*)(sm + L_M1L);
  f16* sM2H = (f16*)(sm + L_M2H);
  f16* sM2L = (f16*)(sm + L_M2L);

  const int tid = threadIdx.x;
  const int lane = tid & 63;
  const int wave = tid >> 6;
  const int col = lane & 15;
  const int quad = lane >> 4;
  const int b = blockIdx.x >> 2;
  const int i0 = (blockIdx.x & 3) << 4;

  char* wsb = (char*)ws;
  float* h_ws = (float*)(wsb + H_OFF);
  const char* W = wsb + WQ_OFF;
  const f16* W2aLOH = (const f16*)(W + O_W2ALOH);
  const f16* W2aLOL = (const f16*)(W + O_W2ALOL);
  const f16* W2aHIH = (const f16*)(W + O_W2AHIH);
  const f16* W2aHIL = (const f16*)(W + O_W2AHIL);
  const float* w45b = (const float*)(W + O_W45B);
  const f16* W2BTH = (const f16*)(W + O_W2BTH);
  const f16* W2BTL = (const f16*)(W + O_W2BTL);
  const float* b2b_g = (const float*)(W + O_B2B);
  const f16* W2CTH = (const f16*)(W + O_W2CTH);
  const f16* W2CTL = (const f16*)(W + O_W2CTL);
  const float* b2c_g = (const float*)(W + O_B2C);
  const float* WxT = (const float*)(W + O_WXT);
  const float* UxT = (const float*)(W + O_UXT);
  const float* bx_g = (const float*)(W + O_BX);
  const float* bh_g = (const float*)(W + O_BH);
  const float* W3bT = (const float*)(W + O_W3BT);
  const float* b3b_g = (const float*)(W + O_B3B);
  const float* W4aT = (const float*)(W + O_W4AT);
  const float* b4a_g = (const float*)(W + O_B4A);
  const float* W4bT = (const float*)(W + O_W4BT);
  const float* b4b_g = (const float*)(W + O_B4B);
  const float* W4cT = (const float*)(W + O_W4CT);
  const float* b4c_g = (const float*)(W + O_B4C);

  const float* nin = node_in + (size_t)b * 2048;

  // ---- P0: node -> /64 hi/lo splits; zero m_i accum ----
  for (int idx = tid; idx < 2048; idx += 256) {
    f16 h_, l_;
    splita(nin[idx], h_, l_);
    sNH[idx] = h_;
    sNL[idx] = l_;
  }
  for (int idx = tid; idx < 512; idx += 256) sMacc[idx] = 0.f;
  __syncthreads();

  // ---- P1: Q (16 src nodes) and P (64 nodes), 3-term split MFMA ----
  {
    const h8 aqh = *(const h8*)(sNH + (i0 + col) * 32 + quad * 8);
    const h8 aql = *(const h8*)(sNL + (i0 + col) * 32 + quad * 8);
    const h8 bqh = *(const h8*)(W2aLOH + (wave * 16 + col) * 32 + quad * 8);
    const h8 bql = *(const h8*)(W2aLOL + (wave * 16 + col) * 32 + quad * 8);
    f4 cq = {0.f, 0.f, 0.f, 0.f};
    cq = MFMA16(aqh, bqh, cq);
    cq = MFMA16(aqh, bql, cq);
    cq = MFMA16(aql, bqh, cq);
#pragma unroll
    for (int r = 0; r < 4; ++r)
      sQf[(quad * 4 + r) * 66 + wave * 16 + col] = cq[r] * 64.f;
    const h8 aph = *(const h8*)(sNH + (wave * 16 + col) * 32 + quad * 8);
    const h8 apl = *(const h8*)(sNL + (wave * 16 + col) * 32 + quad * 8);
#pragma unroll
    for (int nt = 0; nt < 4; ++nt) {
      const h8 bph = *(const h8*)(W2aHIH + (nt * 16 + col) * 32 + quad * 8);
      const h8 bpl = *(const h8*)(W2aHIL + (nt * 16 + col) * 32 + quad * 8);
      f4 cp = {0.f, 0.f, 0.f, 0.f};
      cp = MFMA16(aph, bph, cp);
      cp = MFMA16(aph, bpl, cp);
      cp = MFMA16(apl, bph, cp);
#pragma unroll
      for (int r = 0; r < 4; ++r)
        sPf[(wave * 16 + quad * 4 + r) * 66 + nt * 16 + col] = cp[r] * 64.f;
    }
  }

  // persistent B fragments (hi/lo) for mm2/mm3
  h8 Bbh[2][2], Bbl[2][2], Bch[2], Bcl[2];
#pragma unroll
  for (int nt = 0; nt < 2; ++nt) {
#pragma unroll
    for (int kt = 0; kt < 2; ++kt) {
      Bbh[nt][kt] = *(const h8*)(W2BTH + (nt * 16 + col) * 64 + kt * 32 + quad * 8);
      Bbl[nt][kt] = *(const h8*)(W2BTL + (nt * 16 + col) * 64 + kt * 32 + quad * 8);
    }
    Bch[nt] = *(const h8*)(W2CTH + (nt * 16 + col) * 32 + quad * 8);
    Bcl[nt] = *(const h8*)(W2CTL + (nt * 16 + col) * 32 + quad * 8);
  }
  const float bb2[2] = {b2b_g[col], b2b_g[16 + col]};
  const float bc2[2] = {b2c_g[col], b2c_g[16 + col]};

  // hoisted m1 constants for this thread's u-pair
  const int up = tid & 31;
  const int grp = tid >> 5;  // 0..7
  const float wa0 = w45b[2 * up], wa1 = w45b[2 * up + 1];
  const float wb0 = w45b[64 + 2 * up], wb1 = w45b[64 + 2 * up + 1];
  const float ba0 = w45b[128 + 2 * up], ba1 = w45b[128 + 2 * up + 1];
  __syncthreads();

  // ---- P2: 16 chunks, 1 source node (64 edge slots) each ----
  for (int c = 0; c < 16; ++c) {
    const int ig = i0 + c;
    const float q0 = sQf[c * 66 + 2 * up];
    const float q1 = sQf[c * 66 + 2 * up + 1];
    // m1 assembly (f32) -> /64 hi/lo split
#pragma unroll
    for (int r = 0; r < 8; ++r) {
      const int ko = grp * 8 + r;
      int j = ko + ((ko >= ig) ? 1 : 0);
      j = (j > 63) ? 63 : j;
      float e0 = 0.f, e1 = 0.f;
      if (ko < 63) {
        const float2 ev =
            *(const float2*)(edge + ((size_t)b * 4032 + ig * 63 + ko) * 2);
        e0 = ev.x;
        e1 = ev.y;
      }
      const float p0 = sPf[j * 66 + 2 * up];
      const float p1 = sPf[j * 66 + 2 * up + 1];
      float v0 = q0 + p0 + ba0;
      float v1 = q1 + p1 + ba1;
      v0 = fmaf(e1, wb0, fmaf(e0, wa0, v0));
      v1 = fmaf(e1, wb1, fmaf(e0, wa1, v1));
      const float g0 = gelu_f(v0), g1 = gelu_f(v1);
      f16 h0, l0, h1, l1;
      splita(g0, h0, l0);
      splita(g1, h1, l1);
      sM1H[ko * 72 + 2 * up] = h0;
      sM1H[ko * 72 + 2 * up + 1] = h1;
      sM1L[ko * 72 + 2 * up] = l0;
      sM1L[ko * 72 + 2 * up + 1] = l1;
    }
    __syncthreads();
    // mm2: [64,64]@[64,32], wave handles M-tile `wave`
    {
      const int row = wave * 16 + col;
      const h8 ah0 = *(const h8*)(sM1H + row * 72 + quad * 8);
      const h8 ah1 = *(const h8*)(sM1H + row * 72 + 32 + quad * 8);
      const h8 al0 = *(const h8*)(sM1L + row * 72 + quad * 8);
      const h8 al1 = *(const h8*)(sM1L + row * 72 + 32 + quad * 8);
#pragma unroll
      for (int nt = 0; nt < 2; ++nt) {
        f4 cc = {0.f, 0.f, 0.f, 0.f};
        cc = MFMA16(ah0, Bbh[nt][0], cc);
        cc = MFMA16(ah1, Bbh[nt][1], cc);
        cc = MFMA16(ah0, Bbl[nt][0], cc);
        cc = MFMA16(ah1, Bbl[nt][1], cc);
        cc = MFMA16(al0, Bbh[nt][0], cc);
        cc = MFMA16(al1, Bbh[nt][1], cc);
#pragma unroll
        for (int r = 0; r < 4; ++r) {
          const float g = gelu_f(fmaf(64.f, cc[r], bb2[nt]));
          f16 h_, l_;
          splita(g, h_, l_);
          const int orow = wave * 16 + quad * 4 + r;
          sM2H[orow * 40 + nt * 16 + col] = h_;
          sM2L[orow * 40 + nt * 16 + col] = l_;
        }
      }
    }
    __syncthreads();
    // mm3: [64,32]@[32,32] + segment-sum (exclude dummy slot 63)
    {
      const int row = wave * 16 + col;
      const h8 ah = *(const h8*)(sM2H + row * 40 + quad * 8);
      const h8 al = *(const h8*)(sM2L + row * 40 + quad * 8);
#pragma unroll
      for (int nt = 0; nt < 2; ++nt) {
        f4 cc = {0.f, 0.f, 0.f, 0.f};
        cc = MFMA16(ah, Bch[nt], cc);
        cc = MFMA16(ah, Bcl[nt], cc);
        cc = MFMA16(al, Bch[nt], cc);
        float part = 0.f;
#pragma unroll
        for (int r = 0; r < 4; ++r) {
          const int slot = wave * 16 + quad * 4 + r;
          const float g = gelu_f(fmaf(64.f, cc[r], bc2[nt]));
          part += (slot != 63) ? g : 0.f;
        }
        atomicAdd(&sMacc[c * 32 + nt * 16 + col], part);
      }
    }
    __syncthreads();
  }

  // ---- P3: GRU (f32 VALU) ----
  float* sH32 = (float*)(sm + L_H32);
  float* sR = (float*)(sm + L_R);
  float* sZ = (float*)(sm + L_Z);
  float* sXn = (float*)(sm + L_XN);
  float* sHng = (float*)(sm + L_HNG);
  float* sHn32 = (float*)(sm + L_HN32);

  for (int idx = tid; idx < 1024; idx += 256) {
    const int nl = idx >> 6, k = idx & 63;
    sH32[idx] = h_ws[((size_t)(b * 64 + i0 + nl)) * 64 + k];
  }
  __syncthreads();

  {
    const int n = tid >> 4;
    const int u0 = tid & 15;
    float4 mi4[8], hh4[16];
    const float4* mrow = (const float4*)(sMacc + n * 32);
#pragma unroll
    for (int i = 0; i < 8; ++i) mi4[i] = mrow[i];
    const float4* hrow = (const float4*)(sH32 + n * 64);
#pragma unroll
    for (int i = 0; i < 16; ++i) hh4[i] = hrow[i];
#pragma unroll
    for (int gi = 0; gi < 12; ++gi) {
      const int u = u0 + 16 * gi;
      const float4* wx = (const float4*)(WxT + u * 32);
      float ax = 0.f;
#pragma unroll
      for (int i = 0; i < 8; ++i) {
        const float4 w = wx[i];
        ax = fmaf(mi4[i].x, w.x, ax);
        ax = fmaf(mi4[i].y, w.y, ax);
        ax = fmaf(mi4[i].z, w.z, ax);
        ax = fmaf(mi4[i].w, w.w, ax);
      }
      const float4* ux = (const float4*)(UxT + u * 64);
      float ah = 0.f;
#pragma unroll
      for (int i = 0; i < 16; ++i) {
        const float4 w = ux[i];
        ah = fmaf(hh4[i].x, w.x, ah);
        ah = fmaf(hh4[i].y, w.y, ah);
        ah = fmaf(hh4[i].z, w.z, ah);
        ah = fmaf(hh4[i].w, w.w, ah);
      }
      const float bxv = bx_g[u], bhv = bh_g[u];
      if (u < 64) {
        sR[n * 64 + u] = sigm_f(ax + ah + bxv + bhv);
      } else if (u < 128) {
        sZ[n * 64 + u - 64] = sigm_f(ax + ah + bxv + bhv);
      } else {
        sXn[n * 64 + u - 128] = ax + bxv;
        sHng[n * 64 + u - 128] = ah + bhv;
      }
    }
  }
  __syncthreads();

#pragma unroll
  for (int p = 0; p < 4; ++p) {
    const int nl = wave + 4 * p;
    const int u = lane;
    const float r_ = sR[nl * 64 + u];
    const float z_ = sZ[nl * 64 + u];
    const float n_ = gelu_f(fmaf(r_, sHng[nl * 64 + u], sXn[nl * 64 + u]));
    const float hold = sH32[nl * 64 + u];
    const float hnew = (1.f - z_) * n_ + z_ * hold;
    sHn32[nl * 64 + u] = hnew;
    h_ws[((size_t)(b * 64 + i0 + nl)) * 64 + u] = hnew;
  }
  __syncthreads();

  // ---- P4: node update (f32 VALU) + optional readout ----
  float* sT1 = (float*)(sm + L_T1);
  float* sT2 = (float*)(sm + L_T2);
  float* sNd = (float*)(sm + L_ND);

  for (int t = tid; t < 512; t += 256) {
    const int n = t >> 5, f = t & 31;
    float acc = b3b_g[f];
    const float4* hr = (const float4*)(sHn32 + n * 64);
    const float4* wr = (const float4*)(W3bT + f * 64);
#pragma unroll
    for (int i = 0; i < 16; ++i) {
      const float4 hv = hr[i];
      const float4 wv = wr[i];
      acc = fmaf(hv.x, wv.x, acc);
      acc = fmaf(hv.y, wv.y, acc);
      acc = fmaf(hv.z, wv.z, acc);
      acc = fmaf(hv.w, wv.w, acc);
    }
    if (!is_last)
      node_out[((size_t)(b * 64 + i0 + n)) * 32 + f] = acc;
    else
      sNd[n * 32 + f] = acc;
  }

  if (is_last) {
    __syncthreads();
    // t1 = node@W4a + b4a : [16,32]@[32,64]
    for (int t = tid; t < 1024; t += 256) {
      const int n = t >> 6, u = t & 63;
      float acc = b4a_g[u];
      const float4* ar = (const float4*)(sNd + n * 32);
      const float4* wr = (const float4*)(W4aT + u * 32);
#pragma unroll
      for (int i = 0; i < 8; ++i) {
        const float4 av = ar[i];
        const float4 wv = wr[i];
        acc = fmaf(av.x, wv.x, acc);
        acc = fmaf(av.y, wv.y, acc);
        acc = fmaf(av.z, wv.z, acc);
        acc = fmaf(av.w, wv.w, acc);
      }
      sT1[n * 68 + u] = acc;
    }
    __syncthreads();
    // t2 = t1@W4b + b4b : [16,64]@[64,32]
    for (int t = tid; t < 512; t += 256) {
      const int n = t >> 5, v = t & 31;
      float acc = b4b_g[v];
      const float4* ar = (const float4*)(sT1 + n * 68);
      const float4* wr = (const float4*)(W4bT + v * 64);
#pragma unroll
      for (int i = 0; i < 16; ++i) {
        const float4 av = ar[i];
        const float4 wv = wr[i];
        acc = fmaf(av.x, wv.x, acc);
        acc = fmaf(av.y, wv.y, acc);
        acc = fmaf(av.z, wv.z, acc);
        acc = fmaf(av.w, wv.w, acc);
      }
      sT2[n * 36 + v] = acc;
    }
    __syncthreads();
    // out = t2@W4c + b4c : [16,32]@[32,32]
    for (int t = tid; t < 512; t += 256) {
      const int n = t >> 5, f = t & 31;
      float acc = b4c_g[f];
      const float4* ar = (const float4*)(sT2 + n * 36);
      const float4* wr = (const float4*)(W4cT + f * 32);
#pragma unroll
      for (int i = 0; i < 8; ++i) {
        const float4 av = ar[i];
        const float4 wv = wr[i];
        acc = fmaf(av.x, wv.x, acc);
        acc = fmaf(av.y, wv.y, acc);
        acc = fmaf(av.z, wv.z, acc);
        acc = fmaf(av.w, wv.w, acc);
      }
      out[((size_t)(b * 64 + i0 + n)) * 32 + f] = acc;
    }
  }
}

// ===========================================================================
extern "C" void kernel_launch(void* const* d_in, const int* in_sizes, int n_in,
                              void* d_out, int out_size, void* d_ws, size_t ws_size,
                              hipStream_t stream) {
  (void)in_sizes;
  (void)n_in;
  (void)out_size;
  (void)ws_size;
  const float* node0 = (const float*)d_in[0];
  const float* edge = (const float*)d_in[1];
  // d_in[2], d_in[3] (node_mean, node_vari) unused by the reference
  const float* hin = (const float*)d_in[4];
  const float* W1 = (const float*)d_in[5];
  const float* b1 = (const float*)d_in[6];
  const float* W2a = (const float*)d_in[7];
  const float* b2a = (const float*)d_in[8];
  const float* W2b = (const float*)d_in[9];
  const float* b2b = (const float*)d_in[10];
  const float* W2c = (const float*)d_in[11];
  const float* b2c = (const float*)d_in[12];
  const float* Wx = (const float*)d_in[13];
  const float* Ux = (const float*)d_in[14];
  const float* bx = (const float*)d_in[15];
  const float* bh = (const float*)d_in[16];
  const float* W3b = (const float*)d_in[17];
  const float* b3b = (const float*)d_in[18];
  const float* W4a = (const float*)d_in[19];
  const float* b4a = (const float*)d_in[20];
  const float* W4b = (const float*)d_in[21];
  const float* b4b = (const float*)d_in[22];
  const float* W4c = (const float*)d_in[23];
  const float* b4c = (const float*)d_in[24];
  // d_in[25], d_in[26] (u_is, u_js): edge pattern is closed-form, unused

  float* ws = (float*)d_ws;
  char* wsb = (char*)d_ws;
  float* nodeA = (float*)(wsb + NODEA_OFF);
  float* nodeB = (float*)(wsb + NODEB_OFF);
  float* out = (float*)d_out;

  k_pre<<<dim3(132), dim3(256), 0, stream>>>(node0, hin, W1, b1, W2a, b2a, W2b, b2b,
                                             W2c, b2c, Wx, Ux, bx, bh, W3b, b3b, W4a,
                                             b4a, W4b, b4b, W4c, b4c, ws);
  k_iter<<<dim3(512), dim3(256), 0, stream>>>(edge, ws, nodeA, nodeB, nullptr, 0);
  k_iter<<<dim3(512), dim3(256), 0, stream>>>(edge, ws, nodeB, nodeA, nullptr, 0);
  k_iter<<<dim3(512), dim3(256), 0, stream>>>(edge, ws, nodeA, nullptr, out, 1);
}

// Round 5
// 425.569 us; speedup vs baseline: 1.2761x; 1.2761x over previous
//
#include <hip/hip_runtime.h>

// ---------------------------------------------------------------------------
// GNN forward, MI355X. All I/O f32; split-f16 MFMA numerics (R4, verified).
// R5: barrier-free P2. R4 was latency-bound (VALUBusy 23%, Mfma 2.6%,
// 48 block barriers x 8 waves/CU). Now each WAVE owns whole edge chunks:
//   m1 assembled straight into MFMA A-frag registers (no m1 LDS),
//   mm2 -> wave-private LDS round-trip (C->A layout) guarded by
//   wave_barrier+mem-fence (same-wave DS is in-order in HW),
//   mm3 -> register segment-sum -> 2 LDS atomics/lane/chunk.
// Block barriers: 5/kernel (was ~53). LDS 44.0KB -> 3 blocks/CU.
// k_pre: fc1a over 256 blocks; h-copy dropped (iter1 reads hin directly).
// ---------------------------------------------------------------------------

typedef _Float16 f16;
typedef _Float16 h8 __attribute__((ext_vector_type(8)));
typedef float f4 __attribute__((ext_vector_type(4)));

#define MFMA16(a, b, c) __builtin_amdgcn_mfma_f32_16x16x32_f16(a, b, c, 0, 0, 0)
#define WFENCE()                        \
  do {                                  \
    __builtin_amdgcn_wave_barrier();    \
    __asm__ volatile("" ::: "memory");  \
  } while (0)

// ---- workspace byte offsets ----
#define H_OFF 0              // f32 [128][64][64]
#define NODEA_OFF 2097152    // f32 [128][64][32]
#define NODEB_OFF 3145728    // f32 [128][64][32]
#define WQ_OFF 4194304
// within WQ:
#define O_W2ALOH 0       // f16 [64u][32k] hi of W2a[k][u], k<32
#define O_W2ALOL 4096    // f16 lo
#define O_W2AHIH 8192    // f16 [64u][32k] hi of W2a[32+k][u]
#define O_W2AHIL 12288
#define O_W45B 16384     // f32 w64[64], w65[64], b2a[64]
#define O_W2BTH 17152    // f16 [32v][64k] hi of W2b[k][v]
#define O_W2BTL 21248
#define O_B2B 25344      // f32 [32]
#define O_W2CTH 25472    // f16 [32v][32k]
#define O_W2CTL 27520
#define O_B2C 29568      // f32 [32]
#define O_WXT 29696      // f32 [192u][32k] = Wx[k][u]
#define O_UXT 54272      // f32 [192u][64k] = Ux[k][u]
#define O_BX 103424      // f32 [192]
#define O_BH 104192      // f32 [192]
#define O_W3BT 104960    // f32 [32f][64k] = W3b[k][f]
#define O_B3B 113152     // f32 [32]
#define O_W4AT 113280    // f32 [64u][32k] = W4a[k][u]
#define O_B4A 121472     // f32 [64]
#define O_W4BT 121728    // f32 [32v][64k] = W4b[k][v]
#define O_B4B 129920     // f32 [32]
#define O_W4CT 130048    // f32 [32f][32k] = W4c[k][f]
#define O_B4C 134144     // f32 [32]

// ---- k_iter LDS byte offsets ----
// P0..P2 era:
#define L_NH 0       // f16 [64][32] node/64 hi  (P0..P1)
#define L_NL 4096    // f16 [64][32] node/64 lo  (P0..P1)
#define L_M2W 8192   // per-wave m2 buffers: 4 x 2560 B (hi 1280 | lo 1280) (P2)
#define L_QF 18432   // f32 [16][68] Q+b2a (P1..P2)
#define L_MACC 24576 // f32 [16][32] m_i accum (P0..GRU)
#define L_PF 26624   // f32 [64][68] P (P1..P2)
#define L_TOTAL 44032
// GRU era (over [0,24576), all dead by then):
#define L_H32 0      // f32 [16][64]
#define L_R 4096
#define L_Z 8192
#define L_XN 12288
#define L_HNG 16384
#define L_HN32 20480
// readout era (R/Z/XN/HNG dead):
#define L_ND 4096    // f32 [16][32]
#define L_T1 8192    // f32 [16][68]
#define L_T2 12544   // f32 [16][36]

__device__ __forceinline__ float fast_rcp(float x) {
#if __has_builtin(__builtin_amdgcn_rcpf)
  return __builtin_amdgcn_rcpf(x);
#else
  return 1.0f / x;
#endif
}
// jax.nn.gelu(approximate=True) = x*sigmoid(2*sqrt(2/pi)*(x+0.044715x^3))
__device__ __forceinline__ float gelu_f(float x) {
  float x3 = x * x * x;
  float u = -1.5957691216057308f * fmaf(0.044715f, x3, x);
  return x * fast_rcp(1.f + __expf(u));
}
__device__ __forceinline__ float sigm_f(float x) {
  return fast_rcp(1.f + __expf(-x));
}
__device__ __forceinline__ void splitw(float v, f16& h, f16& l) {
  h = (f16)v;
  l = (f16)(v - (float)h);
}
__device__ __forceinline__ void splita(float v, f16& h, f16& l) {
  float s = v * 0.015625f;
  h = (f16)s;
  l = (f16)(s - (float)h);
}

// ===========================================================================
__global__ __launch_bounds__(256) void k_pre(
    const float* __restrict__ node0, const float* __restrict__ W1,
    const float* __restrict__ b1, const float* __restrict__ W2a,
    const float* __restrict__ b2a, const float* __restrict__ W2b,
    const float* __restrict__ b2b, const float* __restrict__ W2c,
    const float* __restrict__ b2c, const float* __restrict__ Wx,
    const float* __restrict__ Ux, const float* __restrict__ bx,
    const float* __restrict__ bh, const float* __restrict__ W3b,
    const float* __restrict__ b3b, const float* __restrict__ W4a,
    const float* __restrict__ b4a, const float* __restrict__ W4b,
    const float* __restrict__ b4b, const float* __restrict__ W4c,
    const float* __restrict__ b4c, float* __restrict__ ws) {
  const int t = threadIdx.x;
  const int blk = blockIdx.x;
  char* wsb = (char*)ws;
  float* nodeA = (float*)(wsb + NODEA_OFF);
  char* W = wsb + WQ_OFF;

  if (blk < 256) {  // fc1a: 2 blocks per batch, 32 nodes each
    const int b = blk >> 1;
    const int n0 = (blk & 1) << 5;
    for (int idx = t; idx < 1024; idx += 256) {
      const int n = n0 + (idx >> 5), f = idx & 31;
      float acc = b1[f];
#pragma unroll
      for (int k = 0; k < 8; ++k)
        acc = fmaf(node0[((size_t)(b * 64 + n)) * 8 + k], W1[k * 32 + f], acc);
      nodeA[(size_t)b * 2048 + n * 32 + f] = acc;
    }
  } else if (blk == 256) {
    f16* loh = (f16*)(W + O_W2ALOH);
    f16* lol = (f16*)(W + O_W2ALOL);
    f16* hih = (f16*)(W + O_W2AHIH);
    f16* hil = (f16*)(W + O_W2AHIL);
    for (int idx = t; idx < 2048; idx += 256) {
      const int k = idx >> 6, u = idx & 63;
      f16 h_, l_;
      splitw(W2a[k * 64 + u], h_, l_);
      loh[u * 32 + k] = h_;
      lol[u * 32 + k] = l_;
      splitw(W2a[(k + 32) * 64 + u], h_, l_);
      hih[u * 32 + k] = h_;
      hil[u * 32 + k] = l_;
    }
    float* wb = (float*)(W + O_W45B);
    if (t < 64) {
      wb[t] = W2a[64 * 64 + t];
      wb[64 + t] = W2a[65 * 64 + t];
      wb[128 + t] = b2a[t];
    }
    f16* bth = (f16*)(W + O_W2BTH);
    f16* btl = (f16*)(W + O_W2BTL);
    for (int idx = t; idx < 2048; idx += 256) {
      const int k = idx >> 5, v = idx & 31;
      f16 h_, l_;
      splitw(W2b[k * 32 + v], h_, l_);
      bth[v * 64 + k] = h_;
      btl[v * 64 + k] = l_;
    }
    float* b2bf = (float*)(W + O_B2B);
    if (t < 32) b2bf[t] = b2b[t];
    f16* cth = (f16*)(W + O_W2CTH);
    f16* ctl = (f16*)(W + O_W2CTL);
    for (int idx = t; idx < 1024; idx += 256) {
      const int k = idx >> 5, v = idx & 31;
      f16 h_, l_;
      splitw(W2c[k * 32 + v], h_, l_);
      cth[v * 32 + k] = h_;
      ctl[v * 32 + k] = l_;
    }
    float* b2cf = (float*)(W + O_B2C);
    if (t < 32) b2cf[t] = b2c[t];
  } else if (blk == 257) {
    float* wxt = (float*)(W + O_WXT);
    for (int idx = t; idx < 6144; idx += 256) {
      const int u = idx >> 5, k = idx & 31;
      wxt[u * 32 + k] = Wx[k * 192 + u];
    }
    float* bxf = (float*)(W + O_BX);
    float* bhf = (float*)(W + O_BH);
    if (t < 192) {
      bxf[t] = bx[t];
      bhf[t] = bh[t];
    }
  } else if (blk == 258) {
    float* uxt = (float*)(W + O_UXT);
    for (int idx = t; idx < 12288; idx += 256) {
      const int u = idx >> 6, k = idx & 63;
      uxt[u * 64 + k] = Ux[k * 192 + u];
    }
  } else {
    float* w3bt = (float*)(W + O_W3BT);
    for (int idx = t; idx < 2048; idx += 256) {
      const int f = idx >> 6, k = idx & 63;
      w3bt[f * 64 + k] = W3b[k * 32 + f];
    }
    float* b3bf = (float*)(W + O_B3B);
    if (t < 32) b3bf[t] = b3b[t];
    float* w4at = (float*)(W + O_W4AT);
    for (int idx = t; idx < 2048; idx += 256) {
      const int u = idx >> 5, k = idx & 31;
      w4at[u * 32 + k] = W4a[k * 64 + u];
    }
    float* b4af = (float*)(W + O_B4A);
    if (t < 64) b4af[t] = b4a[t];
    float* w4bt = (float*)(W + O_W4BT);
    for (int idx = t; idx < 2048; idx += 256) {
      const int v = idx >> 6, k = idx & 63;
      w4bt[v * 64 + k] = W4b[k * 32 + v];
    }
    float* b4bf = (float*)(W + O_B4B);
    if (t < 32) b4bf[t] = b4b[t];
    float* w4ct = (float*)(W + O_W4CT);
    for (int idx = t; idx < 1024; idx += 256) {
      const int f = idx >> 5, k = idx & 31;
      w4ct[f * 32 + k] = W4c[k * 32 + f];
    }
    float* b4cf = (float*)(W + O_B4C);
    if (t < 32) b4cf[t] = b4c[t];
  }
}

// ===========================================================================
__global__ __launch_bounds__(256) void k_iter(
    const float* __restrict__ edge, float* __restrict__ ws,
    const float* __restrict__ node_in, const float* __restrict__ h_in,
    float* __restrict__ node_out, float* __restrict__ out, const int is_last) {
  __shared__ alignas(16) char sm[L_TOTAL];
  f16* sNH = (f16*)(sm + L_NH);
  f16* sNL = (f16*)(sm + L_NL);
  float* sQf = (float*)(sm + L_QF);
  float* sPf = (float*)(sm + L_PF);
  float* sMacc = (float*)(sm + L_MACC);

  const int tid = threadIdx.x;
  const int lane = tid & 63;
  const int wave = tid >> 6;
  const int col = lane & 15;
  const int quad = lane >> 4;
  const int b = blockIdx.x >> 2;
  const int i0 = (blockIdx.x & 3) << 4;

  char* wsb = (char*)ws;
  float* h_ws = (float*)(wsb + H_OFF);
  const char* W = wsb + WQ_OFF;
  const f16* W2aLOH = (const f16*)(W + O_W2ALOH);
  const f16* W2aLOL = (const f16*)(W + O_W2ALOL);
  const f16* W2aHIH = (const f16*)(W + O_W2AHIH);
  const f16* W2aHIL = (const f16*)(W + O_W2AHIL);
  const float* w45b = (const float*)(W + O_W45B);
  const f16* W2BTH = (const f16*)(W + O_W2BTH);
  const f16* W2BTL = (const f16*)(W + O_W2BTL);
  const float* b2b_g = (const float*)(W + O_B2B);
  const f16* W2CTH = (const f16*)(W + O_W2CTH);
  const f16* W2CTL = (const f16*)(W + O_W2CTL);
  const float* b2c_g = (const float*)(W + O_B2C);
  const float* WxT = (const float*)(W + O_WXT);
  const float* UxT = (const float*)(W + O_UXT);
  const float* bx_g = (const float*)(W + O_BX);
  const float* bh_g = (const float*)(W + O_BH);
  const float* W3bT = (const float*)(W + O_W3BT);
  const float* b3b_g = (const float*)(W + O_B3B);
  const float* W4aT = (const float*)(W + O_W4AT);
  const float* b4a_g = (const float*)(W + O_B4A);
  const float* W4bT = (const float*)(W + O_W4BT);
  const float* b4b_g = (const float*)(W + O_B4B);
  const float* W4cT = (const float*)(W + O_W4CT);
  const float* b4c_g = (const float*)(W + O_B4C);

  const float* nin = node_in + (size_t)b * 2048;

  // ---- P0: node -> /64 hi/lo splits; zero m_i accum ----
  for (int idx = tid; idx < 2048; idx += 256) {
    f16 h_, l_;
    splita(nin[idx], h_, l_);
    sNH[idx] = h_;
    sNL[idx] = l_;
  }
  for (int idx = tid; idx < 512; idx += 256) sMacc[idx] = 0.f;
  __syncthreads();

  // ---- P1: Q(+b2a) and P via 3-term split MFMA (pad rows to 68 f32) ----
  {
    const h8 aqh = *(const h8*)(sNH + (i0 + col) * 32 + quad * 8);
    const h8 aql = *(const h8*)(sNL + (i0 + col) * 32 + quad * 8);
    const h8 bqh = *(const h8*)(W2aLOH + (wave * 16 + col) * 32 + quad * 8);
    const h8 bql = *(const h8*)(W2aLOL + (wave * 16 + col) * 32 + quad * 8);
    f4 cq = {0.f, 0.f, 0.f, 0.f};
    cq = MFMA16(aqh, bqh, cq);
    cq = MFMA16(aqh, bql, cq);
    cq = MFMA16(aql, bqh, cq);
    const float b2av = w45b[128 + wave * 16 + col];
#pragma unroll
    for (int r = 0; r < 4; ++r)
      sQf[(quad * 4 + r) * 68 + wave * 16 + col] = fmaf(64.f, cq[r], b2av);
    const h8 aph = *(const h8*)(sNH + (wave * 16 + col) * 32 + quad * 8);
    const h8 apl = *(const h8*)(sNL + (wave * 16 + col) * 32 + quad * 8);
#pragma unroll
    for (int nt = 0; nt < 4; ++nt) {
      const h8 bph = *(const h8*)(W2aHIH + (nt * 16 + col) * 32 + quad * 8);
      const h8 bpl = *(const h8*)(W2aHIL + (nt * 16 + col) * 32 + quad * 8);
      f4 cp = {0.f, 0.f, 0.f, 0.f};
      cp = MFMA16(aph, bph, cp);
      cp = MFMA16(aph, bpl, cp);
      cp = MFMA16(apl, bph, cp);
#pragma unroll
      for (int r = 0; r < 4; ++r)
        sPf[(wave * 16 + quad * 4 + r) * 68 + nt * 16 + col] = cp[r] * 64.f;
    }
  }

  // persistent B fragments (hi/lo) for mm2/mm3
  h8 Bbh[2][2], Bbl[2][2], Bch[2], Bcl[2];
#pragma unroll
  for (int nt = 0; nt < 2; ++nt) {
#pragma unroll
    for (int kt = 0; kt < 2; ++kt) {
      Bbh[nt][kt] = *(const h8*)(W2BTH + (nt * 16 + col) * 64 + kt * 32 + quad * 8);
      Bbl[nt][kt] = *(const h8*)(W2BTL + (nt * 16 + col) * 64 + kt * 32 + quad * 8);
    }
    Bch[nt] = *(const h8*)(W2CTH + (nt * 16 + col) * 32 + quad * 8);
    Bcl[nt] = *(const h8*)(W2CTL + (nt * 16 + col) * 32 + quad * 8);
  }
  const float bb2[2] = {b2b_g[col], b2b_g[16 + col]};
  const float bc2[2] = {b2c_g[col], b2c_g[16 + col]};
  // per-lane u-octet constants (u = kh*32 + quad*8 + j), hoisted to registers
  f4 wav[2][2], wbv[2][2];
#pragma unroll
  for (int kh = 0; kh < 2; ++kh) {
#pragma unroll
    for (int p = 0; p < 2; ++p) {
      wav[kh][p] = *(const f4*)(w45b + kh * 32 + quad * 8 + p * 4);
      wbv[kh][p] = *(const f4*)(w45b + 64 + kh * 32 + quad * 8 + p * 4);
    }
  }
  // wave-private m2 buffer (hi | lo), 16 rows x 40 f16 each
  f16* m2h = (f16*)(sm + L_M2W + wave * 2560);
  f16* m2l = m2h + 640;

  __syncthreads();

  // ---- P2: wave-owned chunks, zero block barriers ----
  for (int cc2 = 0; cc2 < 4; ++cc2) {
    const int c = wave + 4 * cc2;
    const int ig = i0 + c;
    // Q row (broadcast across cols)
    f4 qb[2][2];
#pragma unroll
    for (int kh = 0; kh < 2; ++kh)
#pragma unroll
      for (int p = 0; p < 2; ++p)
        qb[kh][p] = *(const f4*)(sQf + c * 68 + kh * 32 + quad * 8 + p * 4);
    // edge prefetch (4 slots per lane)
    const float* erow = edge + ((size_t)b * 4032 + (size_t)ig * 63) * 2;
    float ev0[4], ev1[4];
#pragma unroll
    for (int mt = 0; mt < 4; ++mt) {
      const int ko = mt * 16 + col;
      if (ko < 63) {
        const float2 e = *(const float2*)(erow + ko * 2);
        ev0[mt] = e.x;
        ev1[mt] = e.y;
      } else {
        ev0[mt] = 0.f;
        ev1[mt] = 0.f;
      }
    }
    float racc[2] = {0.f, 0.f};
#pragma unroll
    for (int mt = 0; mt < 4; ++mt) {
      const int ko = mt * 16 + col;
      int j = ko + ((ko >= ig) ? 1 : 0);
      j = (j > 63) ? 63 : j;
      const float e0 = ev0[mt], e1 = ev1[mt];
      // m1 A-fragments straight into registers
      h8 ah[2], al[2];
#pragma unroll
      for (int kh = 0; kh < 2; ++kh) {
        const float* prow = sPf + j * 68 + kh * 32 + quad * 8;
        const f4 p0 = *(const f4*)prow;
        const f4 p1 = *(const f4*)(prow + 4);
#pragma unroll
        for (int jj = 0; jj < 4; ++jj) {
          float v = qb[kh][0][jj] + p0[jj];
          v = fmaf(e1, wbv[kh][0][jj], fmaf(e0, wav[kh][0][jj], v));
          float g = gelu_f(v) * 0.015625f;
          f16 hi = (f16)g;
          ah[kh][jj] = hi;
          al[kh][jj] = (f16)(g - (float)hi);
          v = qb[kh][1][jj] + p1[jj];
          v = fmaf(e1, wbv[kh][1][jj], fmaf(e0, wav[kh][1][jj], v));
          g = gelu_f(v) * 0.015625f;
          hi = (f16)g;
          ah[kh][4 + jj] = hi;
          al[kh][4 + jj] = (f16)(g - (float)hi);
        }
      }
      // mm2 (3-term split, K=64)
#pragma unroll
      for (int nt = 0; nt < 2; ++nt) {
        f4 cm = {0.f, 0.f, 0.f, 0.f};
        cm = MFMA16(ah[0], Bbh[nt][0], cm);
        cm = MFMA16(ah[1], Bbh[nt][1], cm);
        cm = MFMA16(ah[0], Bbl[nt][0], cm);
        cm = MFMA16(ah[1], Bbl[nt][1], cm);
        cm = MFMA16(al[0], Bbh[nt][0], cm);
        cm = MFMA16(al[1], Bbh[nt][1], cm);
#pragma unroll
        for (int r = 0; r < 4; ++r) {
          const float g = gelu_f(fmaf(64.f, cm[r], bb2[nt])) * 0.015625f;
          const f16 hi = (f16)g;
          const int o = (quad * 4 + r) * 40 + nt * 16 + col;
          m2h[o] = hi;
          m2l[o] = (f16)(g - (float)hi);
        }
      }
      WFENCE();  // order C-layout writes before A-layout reads (same wave)
      const h8 a2h = *(const h8*)(m2h + col * 40 + quad * 8);
      const h8 a2l = *(const h8*)(m2l + col * 40 + quad * 8);
      WFENCE();  // order reads before next M-tile's writes (WAR)
      // mm3 (3-term split, K=32) + masked register segment-sum
#pragma unroll
      for (int nt = 0; nt < 2; ++nt) {
        f4 dm = {0.f, 0.f, 0.f, 0.f};
        dm = MFMA16(a2h, Bch[nt], dm);
        dm = MFMA16(a2h, Bcl[nt], dm);
        dm = MFMA16(a2l, Bch[nt], dm);
#pragma unroll
        for (int r = 0; r < 4; ++r) {
          const int slot3 = mt * 16 + quad * 4 + r;
          const float g = gelu_f(fmaf(64.f, dm[r], bc2[nt]));
          racc[nt] += (slot3 != 63) ? g : 0.f;
        }
      }
    }
    atomicAdd(&sMacc[c * 32 + col], racc[0]);
    atomicAdd(&sMacc[c * 32 + 16 + col], racc[1]);
  }
  __syncthreads();

  // ---- P3: GRU (f32 VALU) ----
  float* sH32 = (float*)(sm + L_H32);
  float* sR = (float*)(sm + L_R);
  float* sZ = (float*)(sm + L_Z);
  float* sXn = (float*)(sm + L_XN);
  float* sHng = (float*)(sm + L_HNG);
  float* sHn32 = (float*)(sm + L_HN32);

  {
    const int nl = tid >> 4;
    const int k4 = (tid * 4) & 63;
    *(float4*)(sH32 + tid * 4) =
        *(const float4*)(h_in + ((size_t)(b * 64 + i0 + nl)) * 64 + k4);
  }
  __syncthreads();

  {
    const int n = tid >> 4;
    const int u0 = tid & 15;
    float4 mi4[8], hh4[16];
    const float4* mrow = (const float4*)(sMacc + n * 32);
#pragma unroll
    for (int i = 0; i < 8; ++i) mi4[i] = mrow[i];
    const float4* hrow = (const float4*)(sH32 + n * 64);
#pragma unroll
    for (int i = 0; i < 16; ++i) hh4[i] = hrow[i];
#pragma unroll
    for (int gi = 0; gi < 12; ++gi) {
      const int u = u0 + 16 * gi;
      const float4* wx = (const float4*)(WxT + u * 32);
      float ax = 0.f;
#pragma unroll
      for (int i = 0; i < 8; ++i) {
        const float4 w = wx[i];
        ax = fmaf(mi4[i].x, w.x, ax);
        ax = fmaf(mi4[i].y, w.y, ax);
        ax = fmaf(mi4[i].z, w.z, ax);
        ax = fmaf(mi4[i].w, w.w, ax);
      }
      const float4* ux = (const float4*)(UxT + u * 64);
      float ah_ = 0.f;
#pragma unroll
      for (int i = 0; i < 16; ++i) {
        const float4 w = ux[i];
        ah_ = fmaf(hh4[i].x, w.x, ah_);
        ah_ = fmaf(hh4[i].y, w.y, ah_);
        ah_ = fmaf(hh4[i].z, w.z, ah_);
        ah_ = fmaf(hh4[i].w, w.w, ah_);
      }
      const float bxv = bx_g[u], bhv = bh_g[u];
      if (u < 64) {
        sR[n * 64 + u] = sigm_f(ax + ah_ + bxv + bhv);
      } else if (u < 128) {
        sZ[n * 64 + u - 64] = sigm_f(ax + ah_ + bxv + bhv);
      } else {
        sXn[n * 64 + u - 128] = ax + bxv;
        sHng[n * 64 + u - 128] = ah_ + bhv;
      }
    }
  }
  __syncthreads();

#pragma unroll
  for (int p = 0; p < 4; ++p) {
    const int nl = wave + 4 * p;
    const int u = lane;
    const float r_ = sR[nl * 64 + u];
    const float z_ = sZ[nl * 64 + u];
    const float n_ = gelu_f(fmaf(r_, sHng[nl * 64 + u], sXn[nl * 64 + u]));
    const float hold = sH32[nl * 64 + u];
    const float hnew = (1.f - z_) * n_ + z_ * hold;
    sHn32[nl * 64 + u] = hnew;
    h_ws[((size_t)(b * 64 + i0 + nl)) * 64 + u] = hnew;
  }
  __syncthreads();

  // ---- P4: node update (f32 VALU) + optional readout ----
  float* sT1 = (float*)(sm + L_T1);
  float* sT2 = (float*)(sm + L_T2);
  float* sNd = (float*)(sm + L_ND);

  for (int t = tid; t < 512; t += 256) {
    const int n = t >> 5, f = t & 31;
    float acc = b3b_g[f];
    const float4* hr = (const float4*)(sHn32 + n * 64);
    const float4* wr = (const float4*)(W3bT + f * 64);
#pragma unroll
    for (int i = 0; i < 16; ++i) {
      const float4 hv = hr[i];
      const float4 wv = wr[i];
      acc = fmaf(hv.x, wv.x, acc);
      acc = fmaf(hv.y, wv.y, acc);
      acc = fmaf(hv.z, wv.z, acc);
      acc = fmaf(hv.w, wv.w, acc);
    }
    if (!is_last)
      node_out[((size_t)(b * 64 + i0 + n)) * 32 + f] = acc;
    else
      sNd[n * 32 + f] = acc;
  }

  if (is_last) {
    __syncthreads();
    for (int t = tid; t < 1024; t += 256) {
      const int n = t >> 6, u = t & 63;
      float acc = b4a_g[u];
      const float4* ar = (const float4*)(sNd + n * 32);
      const float4* wr = (const float4*)(W4aT + u * 32);
#pragma unroll
      for (int i = 0; i < 8; ++i) {
        const float4 av = ar[i];
        const float4 wv = wr[i];
        acc = fmaf(av.x, wv.x, acc);
        acc = fmaf(av.y, wv.y, acc);
        acc = fmaf(av.z, wv.z, acc);
        acc = fmaf(av.w, wv.w, acc);
      }
      sT1[n * 68 + u] = acc;
    }
    __syncthreads();
    for (int t = tid; t < 512; t += 256) {
      const int n = t >> 5, v = t & 31;
      float acc = b4b_g[v];
      const float4* ar = (const float4*)(sT1 + n * 68);
      const float4* wr = (const float4*)(W4bT + v * 64);
#pragma unroll
      for (int i = 0; i < 16; ++i) {
        const float4 av = ar[i];
        const float4 wv = wr[i];
        acc = fmaf(av.x, wv.x, acc);
        acc = fmaf(av.y, wv.y, acc);
        acc = fmaf(av.z, wv.z, acc);
        acc = fmaf(av.w, wv.w, acc);
      }
      sT2[n * 36 + v] = acc;
    }
    __syncthreads();
    for (int t = tid; t < 512; t += 256) {
      const int n = t >> 5, f = t & 31;
      float acc = b4c_g[f];
      const float4* ar = (const float4*)(sT2 + n * 36);
      const float4* wr = (const float4*)(W4cT + f * 32);
#pragma unroll
      for (int i = 0; i < 8; ++i) {
        const float4 av = ar[i];
        const float4 wv = wr[i];
        acc = fmaf(av.x, wv.x, acc);
        acc = fmaf(av.y, wv.y, acc);
        acc = fmaf(av.z, wv.z, acc);
        acc = fmaf(av.w, wv.w, acc);
      }
      out[((size_t)(b * 64 + i0 + n)) * 32 + f] = acc;
    }
  }
}

// ===========================================================================
extern "C" void kernel_launch(void* const* d_in, const int* in_sizes, int n_in,
                              void* d_out, int out_size, void* d_ws, size_t ws_size,
                              hipStream_t stream) {
  (void)in_sizes;
  (void)n_in;
  (void)out_size;
  (void)ws_size;
  const float* node0 = (const float*)d_in[0];
  const float* edge = (const float*)d_in[1];
  const float* hin = (const float*)d_in[4];
  const float* W1 = (const float*)d_in[5];
  const float* b1 = (const float*)d_in[6];
  const float* W2a = (const float*)d_in[7];
  const float* b2a = (const float*)d_in[8];
  const float* W2b = (const float*)d_in[9];
  const float* b2b = (const float*)d_in[10];
  const float* W2c = (const float*)d_in[11];
  const float* b2c = (const float*)d_in[12];
  const float* Wx = (const float*)d_in[13];
  const float* Ux = (const float*)d_in[14];
  const float* bx = (const float*)d_in[15];
  const float* bh = (const float*)d_in[16];
  const float* W3b = (const float*)d_in[17];
  const float* b3b = (const float*)d_in[18];
  const float* W4a = (const float*)d_in[19];
  const float* b4a = (const float*)d_in[20];
  const float* W4b = (const float*)d_in[21];
  const float* b4b = (const float*)d_in[22];
  const float* W4c = (const float*)d_in[23];
  const float* b4c = (const float*)d_in[24];

  float* ws = (float*)d_ws;
  char* wsb = (char*)d_ws;
  float* h_ws = (float*)(wsb + H_OFF);
  float* nodeA = (float*)(wsb + NODEA_OFF);
  float* nodeB = (float*)(wsb + NODEB_OFF);
  float* out = (float*)d_out;

  k_pre<<<dim3(260), dim3(256), 0, stream>>>(node0, W1, b1, W2a, b2a, W2b, b2b, W2c,
                                             b2c, Wx, Ux, bx, bh, W3b, b3b, W4a, b4a,
                                             W4b, b4b, W4c, b4c, ws);
  k_iter<<<dim3(512), dim3(256), 0, stream>>>(edge, ws, nodeA, hin, nodeB, nullptr, 0);
  k_iter<<<dim3(512), dim3(256), 0, stream>>>(edge, ws, nodeB, h_ws, nodeA, nullptr, 0);
  k_iter<<<dim3(512), dim3(256), 0, stream>>>(edge, ws, nodeA, h_ws, nullptr, out, 1);
}